// Round 10
// baseline (125.784 us; speedup 1.0000x reference)
//
#include <hip/hip_runtime.h>

typedef unsigned long long u64;

#define HH 1024
#define WW 2048
#define NN (HH*WW)
#define GRID 512
#define BLOCK 256
#define PXT 16
#define CHUNK (PXT*BLOCK)       // 4096 pixels per block

// One-hop flat exchange, fence-free. Per barrier each block stores 2 tagged
// u64 slots (double-buffered by token parity) and bumps a spread arrival
// counter. Blocks poll ONLY the 16 counter lines (tiny traffic), then do one
// validated sweep of the tagged slots (tags authoritative; done-mask catches
// counter/store visibility reordering).
//  A-slot: [tag:12][f32bits(bv):30][NN-1-idx:21]  (u64 max == argmax, min-idx tiebreak)
//  B-slot: [tag:12][zero:13][lps:13][lin:13][lu:13]
struct Coord {
  u64 A[2][GRID];
  u64 B[2][GRID];
  int cnt[16][16];              // 16 monotonic counters, 64B apart ([j][0] used)
};

// XLA expands logistic(x) as 0.5 + 0.5*tanh(0.5*x) — match that boundary.
__device__ __forceinline__ float sigmoid_ref(float x) {
  #pragma clang fp contract(off)
  return 0.5f + 0.5f * tanhf(0.5f * x);
}

__device__ __forceinline__ void slot_store(u64* p, u64 v) {
  __hip_atomic_store(p, v, __ATOMIC_RELAXED, __HIP_MEMORY_SCOPE_AGENT);
}
__device__ __forceinline__ u64 slot_load(u64* p) {
  return __hip_atomic_load(p, __ATOMIC_RELAXED, __HIP_MEMORY_SCOPE_AGENT);
}

// poll the 16 counter lines until the grid-wide arrival total reaches target
__device__ __forceinline__ void wait_count(Coord* __restrict__ c, int lane, int target) {
  for (;;) {
    int v = 0;
    if (lane < 16)
      v = __hip_atomic_load(&c->cnt[lane][0], __ATOMIC_RELAXED, __HIP_MEMORY_SCOPE_AGENT);
    #pragma unroll
    for (int off = 8; off; off >>= 1) v += __shfl_xor(v, off);
    if (__shfl(v, 0) >= target) break;
    __builtin_amdgcn_s_sleep(1);
  }
}

__device__ void barrier_exchange(Coord* __restrict__ c, const float* __restrict__ pred,
                                 int b, int t, int tok,
                                 float bv, int bi, int lu, int lps, int lin,
                                 float& sval, int& sidx, int& uncl, int& psum, int& inter,
                                 float& cx, float& cy, float& s0, float& s1)
{
  #pragma clang fp contract(off)
  __shared__ u64 wA[2][4], wS[2][4];
  __shared__ u64 shA[2], shB[2];
  __shared__ int shLU[2];
  const int par = tok & 1, w = t >> 6, lane = t & 63;
  const unsigned tg = (unsigned)tok & 0xFFFu;
  const int target = tok * GRID;

  // ---- block-local reduce: 2 packed butterflies ----
  unsigned fb = 0; int ic = 0;
  if (bv >= 0.0f) { fb = __float_as_uint(bv); ic = bi; }   // empty -> (0.0, idx 0)
  u64 am = ((u64)fb << 21) | (u64)(unsigned)(NN - 1 - ic);
  u64 sm = ((u64)(unsigned)lps << 42) | ((u64)(unsigned)lin << 21) | (u64)(unsigned)lu;
  for (int off = 32; off; off >>= 1) {
    u64 o = __shfl_xor(am, off);
    if (o > am) am = o;
    sm += __shfl_xor(sm, off);
  }
  if (lane == 0) { wA[par][w] = am; wS[par][w] = sm; }
  __syncthreads();

  if (w == 0) {
    // combine 4 waves + store both slots + bump arrival counter (lane 0)
    u64 A0 = wA[par][0], S0 = wS[par][0];
    #pragma unroll
    for (int j = 1; j < 4; ++j) {
      if (wA[par][j] > A0) A0 = wA[par][j];
      S0 += wS[par][j];
    }
    if (lane == 0) {
      u64 bp = ((u64)tg << 52) | ((S0 >> 42) << 26) |
               (((S0 >> 21) & 0x1FFFu) << 13) | (S0 & 0x1FFFu);
      slot_store(&c->A[par][b], ((u64)tg << 52) | A0);
      slot_store(&c->B[par][b], bp);
      __hip_atomic_fetch_add(&c->cnt[b & 15][0], 1,
                             __ATOMIC_RELAXED, __HIP_MEMORY_SCOPE_AGENT);
    }
    wait_count(c, lane, target);
    // one validated sweep of all A-slots (8 per lane); stragglers re-polled
    u64 q0=0,q1=0,q2=0,q3=0,q4=0,q5=0,q6=0,q7=0;
    unsigned done = 0;
    u64* basep = &c->A[par][lane * 8];
    while (done != 0xFFu) {
      #define POLL(J, QV) if (!((done >> J) & 1u)) { \
        u64 v = slot_load(basep + J); \
        if ((unsigned)(v >> 52) == tg) { QV = v; done |= 1u << J; } }
      POLL(0,q0) POLL(1,q1) POLL(2,q2) POLL(3,q3)
      POLL(4,q4) POLL(5,q5) POLL(6,q6) POLL(7,q7)
      #undef POLL
      if (done != 0xFFu) __builtin_amdgcn_s_sleep(1);
    }
    u64 m = q0;
    if (q1 > m) m = q1; if (q2 > m) m = q2; if (q3 > m) m = q3;
    if (q4 > m) m = q4; if (q5 > m) m = q5; if (q6 > m) m = q6; if (q7 > m) m = q7;
    for (int off = 32; off; off >>= 1) { u64 o = __shfl_xor(m, off); if (o > m) m = o; }
    if (lane == 0) shA[par] = m & ~(0xFFFull << 52);   // strip tag
  } else if (w == 1) {
    wait_count(c, lane, target);
    // one validated sweep of all B-slots
    u64 q0=0,q1=0,q2=0,q3=0,q4=0,q5=0,q6=0,q7=0;
    unsigned done = 0;
    u64* basep = &c->B[par][lane * 8];
    while (done != 0xFFu) {
      #define POLL(J, QV) if (!((done >> J) & 1u)) { \
        u64 v = slot_load(basep + J); \
        if ((unsigned)(v >> 52) == tg) { QV = v; done |= 1u << J; } }
      POLL(0,q0) POLL(1,q1) POLL(2,q2) POLL(3,q3)
      POLL(4,q4) POLL(5,q5) POLL(6,q6) POLL(7,q7)
      #undef POLL
      if (done != 0xFFu) __builtin_amdgcn_s_sleep(1);
    }
    int lp = 0, ln = 0, lq = 0;
    #define ACC(QV) lp += (int)((QV >> 26) & 0x1FFFu); \
                    ln += (int)((QV >> 13) & 0x1FFFu); \
                    lq += (int)(QV & 0x1FFFu);
    ACC(q0) ACC(q1) ACC(q2) ACC(q3) ACC(q4) ACC(q5) ACC(q6) ACC(q7)
    #undef ACC
    u64 pk = ((u64)(unsigned)lp << 32) | (u64)(unsigned)ln;
    for (int off = 32; off; off >>= 1) { pk += __shfl_xor(pk, off); lq += __shfl_xor(lq, off); }
    if (lane == 0) { shB[par] = pk; shLU[par] = lq; }
  }
  __syncthreads();

  u64 m = shA[par];
  sval = __uint_as_float((unsigned)((m >> 21) & 0x3FFFFFFFu));
  int fi = NN - 1 - (int)(m & 0x1FFFFFu);
  sidx = fi;
  u64 pk = shB[par];
  psum = (int)(pk >> 32); inter = (int)(pk & 0xFFFFFFFFu); uncl = shLU[par];
  // center + sigma: every thread recomputes identically (read-only pred,
  // same op order -> grid-consistent, identical math to the reference)
  cx = tanhf(pred[fi])      + (2.0f / 2047.0f) * (float)(fi & (WW - 1));
  cy = tanhf(pred[NN + fi]) + (1.0f / 1023.0f) * (float)(fi >> 11);
  s0 = expf(pred[2 * NN + fi] * 10.0f);
  s1 = expf(pred[3 * NN + fi] * 10.0f);
}

__global__ void init_kernel(Coord* c) {
  int t = blockIdx.x * blockDim.x + threadIdx.x;
  u64* p = (u64*)c;
  int n = (int)(sizeof(Coord) / 8);
  if (t < n) p[t] = 0;
}

__global__ __launch_bounds__(BLOCK, 2)
void cluster_kernel(const float* __restrict__ pred,
                    int* __restrict__ out,
                    Coord* __restrict__ c)
{
  #pragma clang fp contract(off)
  const int b = blockIdx.x, t = threadIdx.x;
  const int base = b * CHUNK;

  const float xstep = 2.0f / 2047.0f;   // jnp.linspace(0,2,2048) step, f32
  const float ystep = 1.0f / 1023.0f;   // jnp.linspace(0,1,1024) step, f32

  // ---- stage 1: load once, keep everything in registers ----
  float ex[PXT], ey[PXT], sd[PXT];
  unsigned mbits = 0, ubits;
  float bv = -1.0f; int bi = 0; int mc = 0;
  #pragma unroll
  for (int k = 0; k < PXT; ++k) {
    int i = base + t + k * BLOCK;
    float seed = sigmoid_ref(pred[6 * NN + i]);
    sd[k] = seed;
    unsigned m = (seed > 0.5f) ? 1u : 0u;
    mbits |= m << k;
    ex[k] = tanhf(pred[i])      + xstep * (float)(i & (WW - 1));
    ey[k] = tanhf(pred[NN + i]) + ystep * (float)(i >> 11);
    out[i] = 0;
    mc += (int)m;
    float scv = m ? seed : 0.0f;
    if (scv > bv) { bv = scv; bi = i; }  // i increasing -> first max kept
  }
  ubits = mbits;

  float sval, cx, cy, s0, s1; int sidx, un, psum, inter;
  int tok = 1;
  barrier_exchange(c, pred, b, t, tok, bv, bi, mc, 0, 0,
                   sval, sidx, un, psum, inter, cx, cy, s0, s1); tok++;

  // ---- main loop: one flat fence-free barrier per iteration ----
  int count = 1;
  unsigned prev_pr = 0;
  for (int it = 0; it < 4000; ++it) {   // cap < 4096 so tag never aliases init 0
    // deferred label write for the previous segment (before break checks!)
    if (it) {
      bool accept = (psum > 160) &&
                    ((float)inter / (float)(psum > 1 ? psum : 1) > 0.5f);
      if (accept) {
        #pragma unroll
        for (int k = 0; k < PXT; ++k)
          if ((prev_pr >> k) & 1u) out[base + t + k * BLOCK] = count;
        count++;
      }
    }
    if (un <= 160) break;          // cond: uncl.sum() > min_pixel
    if (!(sval >= 0.5f)) break;    // go == false -> stop, no state change

    // seed-pixel bit within this thread's pixels (i = base + t + k*BLOCK)
    int rel = sidx - base;
    unsigned sbit = 0;
    if (rel >= 0 && rel < CHUNK && (rel & (BLOCK - 1)) == t)
      sbit = 1u << (rel >> 8);

    // proposal bits (decision-path math identical to reference)
    unsigned pr = 0;
    #pragma unroll
    for (int k = 0; k < PXT; ++k) {
      float dx = ex[k] - cx, dy = ey[k] - cy;
      float dsq = (dx * dx) * s0 + (dy * dy) * s1;
      float dist = expf(-dsq);
      pr |= ((dist > 0.5f) ? 1u : 0u) << k;
    }
    pr &= mbits;
    int lps = __popc(pr);
    int lin = __popc(pr & ubits & ~sbit);  // uncl2 & proposal
    ubits &= ~pr; ubits &= ~sbit;          // uncl_new
    int lu = __popc(ubits);

    // next-seed argmax over remaining unclustered (static indices only)
    bv = -1.0f; bi = 0;
    #pragma unroll
    for (int k = 0; k < PXT; ++k) {
      if (((ubits >> k) & 1u) && sd[k] > bv) { bv = sd[k]; bi = base + t + k * BLOCK; }
    }
    prev_pr = pr;
    barrier_exchange(c, pred, b, t, tok, bv, bi, lu, lps, lin,
                     sval, sidx, un, psum, inter, cx, cy, s0, s1); tok++;
  }
}

extern "C" void kernel_launch(void* const* d_in, const int* in_sizes, int n_in,
                              void* d_out, int out_size, void* d_ws, size_t ws_size,
                              hipStream_t stream) {
  const float* pred = (const float*)d_in[0];
  int* out = (int*)d_out;
  Coord* c = (Coord*)d_ws;

  init_kernel<<<dim3((unsigned)((sizeof(Coord)/8 + 255)/256)), dim3(256), 0, stream>>>(c);

  // Normal launch: co-residency of 512 blocks at 2 blocks/CU is guaranteed by
  // __launch_bounds__(256,2) (VGPR<=256, small LDS) on 256 CUs.
  cluster_kernel<<<dim3(GRID), dim3(BLOCK), 0, stream>>>(pred, out, c);
}

// Round 11
// 69.819 us; speedup vs baseline: 1.8016x; 1.8016x over previous
//
#include <hip/hip_runtime.h>

typedef unsigned long long u64;

#define HH 1024
#define WW 2048
#define NN (HH*WW)
#define GRID 256
#define BLOCK 512
#define PXT 16
#define CHUNK (PXT*BLOCK)       // 8192 pixels per block

// r7-topology barrier, slimmed. Per barrier each block stores 2 packed tagged
// u64 slots (parity double-buffered). Aggregator block 0: one slot per thread
// (t<256 -> A[t], t>=256 -> B[t-256]), packed butterfly reduce, then ONE pub
// u64 carrying the decisions; every other block has a single poller thread on
// that one line. Relaxed tagged atomics -> zero fences.
//  A-slot: [tag:12][f32bits(val):30][NN-1-idx:21]  (u64 max == first-idx argmax)
//  B-slot: [tag:12][lps:14][lin:14][lu:14]         (block totals <= 8192)
//  pub   : [tag:12][spare:7][go:1][acc:1][uncl:22][idx:21]
struct Coord {
  u64 A[2][GRID];
  u64 B[2][GRID];
  u64 pub[2][8];                // [par][0] used; parity slots on separate lines
};

// XLA expands logistic(x) as 0.5 + 0.5*tanh(0.5*x) — match that boundary.
__device__ __forceinline__ float sigmoid_ref(float x) {
  #pragma clang fp contract(off)
  return 0.5f + 0.5f * tanhf(0.5f * x);
}

__device__ __forceinline__ void slot_store(u64* p, u64 v) {
  __hip_atomic_store(p, v, __ATOMIC_RELAXED, __HIP_MEMORY_SCOPE_AGENT);
}
__device__ __forceinline__ u64 slot_load(u64* p) {
  return __hip_atomic_load(p, __ATOMIC_RELAXED, __HIP_MEMORY_SCOPE_AGENT);
}

__device__ void barrier_exchange(Coord* __restrict__ c, const float* __restrict__ pred,
                                 int b, int t, int tok,
                                 float bv, int bi, int lu, int lps, int lin,
                                 int& sidx, int& un, int& go, int& acc,
                                 float& cx, float& cy, float& s0, float& s1)
{
  #pragma clang fp contract(off)
  __shared__ u64 wA[8], wS[8];
  __shared__ int wU[8];
  __shared__ u64 pubsh;
  const int par = tok & 1, w = t >> 6, lane = t & 63;
  const u64 tg = (u64)(unsigned)(tok & 0xFFF);

  // ---- block-local packed reduce (2 butterflies) ----
  unsigned fb = 0; int ic = 0;
  if (bv >= 0.0f) { fb = __float_as_uint(bv); ic = bi; }   // empty -> (0.0, idx 0)
  u64 am = ((u64)fb << 21) | (u64)(unsigned)(NN - 1 - ic);
  u64 sm = ((u64)(unsigned)lps << 42) | ((u64)(unsigned)lin << 21) | (u64)(unsigned)lu;
  for (int off = 32; off; off >>= 1) {
    u64 o = __shfl_xor(am, off); if (o > am) am = o;
    sm += __shfl_xor(sm, off);
  }
  if (lane == 0) { wA[w] = am; wS[w] = sm; }
  __syncthreads();
  if (t == 0) {
    u64 A0 = wA[0], S0 = wS[0];
    #pragma unroll
    for (int j = 1; j < 8; ++j) { if (wA[j] > A0) A0 = wA[j]; S0 += wS[j]; }
    slot_store(&c->A[par][b], (tg << 52) | A0);
    slot_store(&c->B[par][b], (tg << 52) | ((S0 >> 42) << 28) |
                              (((S0 >> 21) & 0x3FFFull) << 14) | (S0 & 0x3FFFull));
  }
  __syncthreads();   // protect wA/wS reads above from gather-phase writes below

  if (b == 0) {
    // ---- arrival gather: exactly one slot per thread, no sweep ----
    u64 got;
    if (t < GRID) {
      u64* p = &c->A[par][t];
      while (((got = slot_load(p)) >> 52) != tg) __builtin_amdgcn_s_sleep(1);
      got &= (1ull << 52) - 1;
      for (int off = 32; off; off >>= 1) { u64 o = __shfl_xor(got, off); if (o > got) got = o; }
      if (lane == 0) wA[w] = got;                       // waves 0..3
    } else {
      u64* p = &c->B[par][t - GRID];
      while (((got = slot_load(p)) >> 52) != tg) __builtin_amdgcn_s_sleep(1);
      int lp = (int)((got >> 28) & 0x3FFFull);
      int ln = (int)((got >> 14) & 0x3FFFull);
      int lq = (int)(got & 0x3FFFull);
      u64 pk = ((u64)(unsigned)lp << 32) | (unsigned)ln;
      for (int off = 32; off; off >>= 1) { pk += __shfl_xor(pk, off); lq += __shfl_xor(lq, off); }
      if (lane == 0) { wS[w] = pk; wU[w] = lq; }        // waves 4..7
    }
    __syncthreads();
    if (t == 0) {
      u64 A0 = wA[0];
      #pragma unroll
      for (int j = 1; j < 4; ++j) if (wA[j] > A0) A0 = wA[j];
      u64 PK = wS[4] + wS[5] + wS[6] + wS[7];
      int UN = wU[4] + wU[5] + wU[6] + wU[7];
      int psum = (int)(PK >> 32), inter = (int)(PK & 0xFFFFFFFFull);
      int idx = NN - 1 - (int)(A0 & 0x1FFFFFull);
      float sv = __uint_as_float((unsigned)(A0 >> 21));
      // accept: (float)inter/(float)max(psum,1) > 0.5f  <=>  2*inter > psum
      // (exact for 1 <= psum <= 2^21: ratio is >= 2^-22 away from 0.5 >> f32 ulp)
      int g = (sv >= 0.5f) ? 1 : 0;
      int a = (psum > 160 && 2 * inter > psum) ? 1 : 0;
      u64 pb = (tg << 52) | ((u64)(unsigned)g << 44) | ((u64)(unsigned)a << 43) |
               ((u64)(unsigned)UN << 21) | (u64)(unsigned)idx;
      slot_store(&c->pub[par][0], pb);
      pubsh = pb;
    }
    __syncthreads();
  } else {
    // ---- one poller thread per block on the single hot pub line ----
    if (t == 0) {
      u64 v;
      while (((v = slot_load(&c->pub[par][0])) >> 52) != tg) __builtin_amdgcn_s_sleep(1);
      pubsh = v;
    }
    __syncthreads();
  }

  u64 v = pubsh;
  sidx = (int)(v & 0x1FFFFFull);
  un   = (int)((v >> 21) & 0x3FFFFFull);
  acc  = (int)((v >> 43) & 1ull);
  go   = (int)((v >> 44) & 1ull);
  // center + sigma: recomputed identically by every thread (read-only pred,
  // same op order as the reference -> grid-consistent decisions)
  cx = tanhf(pred[sidx])      + (2.0f / 2047.0f) * (float)(sidx & (WW - 1));
  cy = tanhf(pred[NN + sidx]) + (1.0f / 1023.0f) * (float)(sidx >> 11);
  s0 = expf(pred[2 * NN + sidx] * 10.0f);
  s1 = expf(pred[3 * NN + sidx] * 10.0f);
}

__global__ void init_kernel(Coord* c) {
  int t = blockIdx.x * blockDim.x + threadIdx.x;
  u64* p = (u64*)c;
  int n = (int)(sizeof(Coord) / 8);
  if (t < n) p[t] = 0;
}

__global__ __launch_bounds__(BLOCK, 1)
void cluster_kernel(const float* __restrict__ pred,
                    int* __restrict__ out,
                    Coord* __restrict__ c)
{
  #pragma clang fp contract(off)
  const int b = blockIdx.x, t = threadIdx.x;
  const int base = b * CHUNK;

  const float xstep = 2.0f / 2047.0f;   // jnp.linspace(0,2,2048) step, f32
  const float ystep = 1.0f / 1023.0f;   // jnp.linspace(0,1,1024) step, f32

  // ---- stage 1: load once, keep everything in registers ----
  float ex[PXT], ey[PXT], sd[PXT];
  unsigned mbits = 0, ubits;
  float bv = -1.0f; int bi = 0; int mc = 0;
  #pragma unroll
  for (int k = 0; k < PXT; ++k) {
    int i = base + t + k * BLOCK;
    float seed = sigmoid_ref(pred[6 * NN + i]);
    sd[k] = seed;
    unsigned m = (seed > 0.5f) ? 1u : 0u;
    mbits |= m << k;
    ex[k] = tanhf(pred[i])      + xstep * (float)(i & (WW - 1));
    ey[k] = tanhf(pred[NN + i]) + ystep * (float)(i >> 11);
    out[i] = 0;
    mc += (int)m;
    float scv = m ? seed : 0.0f;
    if (scv > bv) { bv = scv; bi = i; }  // i increasing -> first max kept
  }
  ubits = mbits;

  int sidx, un, go, acc; float cx, cy, s0, s1;
  int tok = 1;
  barrier_exchange(c, pred, b, t, tok, bv, bi, mc, 0, 0,
                   sidx, un, go, acc, cx, cy, s0, s1); tok++;

  // ---- main loop: one slim two-hop barrier per iteration ----
  int count = 1;
  unsigned prev_pr = 0;
  for (int it = 0; it < 4000; ++it) {   // cap < 4096 so tag never aliases init 0
    // deferred label write for the previous segment (before break checks!)
    if (it && acc) {
      #pragma unroll
      for (int k = 0; k < PXT; ++k)
        if ((prev_pr >> k) & 1u) out[base + t + k * BLOCK] = count;
      count++;
    }
    if (un <= 160) break;          // cond: uncl.sum() > min_pixel
    if (!go) break;                // go == false -> stop, no state change

    // seed-pixel bit within this thread's pixels (i = base + t + k*BLOCK)
    int rel = sidx - base;
    unsigned sbit = 0;
    if (rel >= 0 && rel < CHUNK && (rel & (BLOCK - 1)) == t)
      sbit = 1u << (rel >> 9);     // k = rel / BLOCK

    // proposal bits (decision-path math identical to reference)
    unsigned pr = 0;
    #pragma unroll
    for (int k = 0; k < PXT; ++k) {
      float dx = ex[k] - cx, dy = ey[k] - cy;
      float dsq = (dx * dx) * s0 + (dy * dy) * s1;
      float dist = expf(-dsq);
      pr |= ((dist > 0.5f) ? 1u : 0u) << k;
    }
    pr &= mbits;
    int lps = __popc(pr);
    int lin = __popc(pr & ubits & ~sbit);  // uncl2 & proposal
    ubits &= ~pr; ubits &= ~sbit;          // uncl_new
    int lu = __popc(ubits);

    // next-seed argmax over remaining unclustered (static indices only)
    bv = -1.0f; bi = 0;
    #pragma unroll
    for (int k = 0; k < PXT; ++k) {
      if (((ubits >> k) & 1u) && sd[k] > bv) { bv = sd[k]; bi = base + t + k * BLOCK; }
    }
    prev_pr = pr;
    barrier_exchange(c, pred, b, t, tok, bv, bi, lu, lps, lin,
                     sidx, un, go, acc, cx, cy, s0, s1); tok++;
  }
}

extern "C" void kernel_launch(void* const* d_in, const int* in_sizes, int n_in,
                              void* d_out, int out_size, void* d_ws, size_t ws_size,
                              hipStream_t stream) {
  const float* pred = (const float*)d_in[0];
  int* out = (int*)d_out;
  Coord* c = (Coord*)d_ws;

  init_kernel<<<dim3((unsigned)((sizeof(Coord)/8 + 255)/256)), dim3(256), 0, stream>>>(c);

  // Normal launch: 256 blocks x 512 threads = 1 block/CU on 256 CUs (8 waves/CU,
  // same as before). Co-residency resource-guaranteed; no cooperative pre-check.
  cluster_kernel<<<dim3(GRID), dim3(BLOCK), 0, stream>>>(pred, out, c);
}

// Round 12
// 66.614 us; speedup vs baseline: 1.8882x; 1.0481x over previous
//
#include <hip/hip_runtime.h>

typedef unsigned long long u64;

#define HH 1024
#define WW 2048
#define NN (HH*WW)
#define GRID 256
#define BLOCK 512
#define PXT 16
#define CHUNK (PXT*BLOCK)       // 8192 pixels per block

// Two-hop asymmetric barrier (r11 topology) with replicated pub lines.
//  A-slot: [tag:12][f32bits(val):30][NN-1-idx:21]  (u64 max == first-idx argmax)
//  B-slot: [tag:12][lps:14][lin:14][lu:14]         (block totals <= 8192)
//  pub   : [tag:12][spare:7][go:1][acc:1][uncl:22][idx:21], replicated x8
struct Coord {
  u64 A[2][GRID];
  u64 B[2][GRID];
  u64 pub[2][8][16];            // [par][replica][0] used; 128B-spaced lines
};

// XLA expands logistic(x) as 0.5 + 0.5*tanh(0.5*x) — match that boundary.
__device__ __forceinline__ float sigmoid_ref(float x) {
  #pragma clang fp contract(off)
  return 0.5f + 0.5f * tanhf(0.5f * x);
}

__device__ __forceinline__ void slot_store(u64* p, u64 v) {
  __hip_atomic_store(p, v, __ATOMIC_RELAXED, __HIP_MEMORY_SCOPE_AGENT);
}
__device__ __forceinline__ u64 slot_load(u64* p) {
  return __hip_atomic_load(p, __ATOMIC_RELAXED, __HIP_MEMORY_SCOPE_AGENT);
}

__device__ void barrier_exchange(Coord* __restrict__ c, const float* __restrict__ pred,
                                 int b, int t, int tok,
                                 float bv, int bi, int lu, int lps, int lin,
                                 int& sidx, int& un, int& go, int& acc,
                                 float& cx, float& cy, float& s0, float& s1)
{
  #pragma clang fp contract(off)
  __shared__ u64 wA[8], wS[8];
  __shared__ int wU[8];
  const int par = tok & 1, w = t >> 6, lane = t & 63;
  const u64 tg = (u64)(unsigned)(tok & 0xFFF);

  // ---- block-local packed reduce (2 butterflies) ----
  unsigned fb = 0; int ic = 0;
  if (bv >= 0.0f) { fb = __float_as_uint(bv); ic = bi; }   // empty -> (0.0, idx 0)
  u64 am = ((u64)fb << 21) | (u64)(unsigned)(NN - 1 - ic);
  u64 sm = ((u64)(unsigned)lps << 42) | ((u64)(unsigned)lin << 21) | (u64)(unsigned)lu;
  for (int off = 32; off; off >>= 1) {
    u64 o = __shfl_xor(am, off); if (o > am) am = o;
    sm += __shfl_xor(sm, off);
  }
  if (lane == 0) { wA[w] = am; wS[w] = sm; }
  __syncthreads();
  if (t == 0) {
    u64 A0 = wA[0], S0 = wS[0];
    #pragma unroll
    for (int j = 1; j < 8; ++j) { if (wA[j] > A0) A0 = wA[j]; S0 += wS[j]; }
    slot_store(&c->A[par][b], (tg << 52) | A0);
    slot_store(&c->B[par][b], (tg << 52) | ((S0 >> 42) << 28) |
                              (((S0 >> 21) & 0x3FFFull) << 14) | (S0 & 0x3FFFull));
  }
  __syncthreads();   // t0's wA/wS reads done before gather phase reuses them

  if (b == 0) {
    // ---- arrival gather: exactly one slot per thread ----
    u64 got;
    if (t < GRID) {
      u64* p = &c->A[par][t];
      while (((got = slot_load(p)) >> 52) != tg) __builtin_amdgcn_s_sleep(1);
      got &= (1ull << 52) - 1;
      for (int off = 32; off; off >>= 1) { u64 o = __shfl_xor(got, off); if (o > got) got = o; }
      if (lane == 0) wA[w] = got;                       // waves 0..3
    } else {
      u64* p = &c->B[par][t - GRID];
      while (((got = slot_load(p)) >> 52) != tg) __builtin_amdgcn_s_sleep(1);
      int lp = (int)((got >> 28) & 0x3FFFull);
      int ln = (int)((got >> 14) & 0x3FFFull);
      int lq = (int)(got & 0x3FFFull);
      u64 pk = ((u64)(unsigned)lp << 32) | (unsigned)ln;
      for (int off = 32; off; off >>= 1) { pk += __shfl_xor(pk, off); lq += __shfl_xor(lq, off); }
      if (lane == 0) { wS[w] = pk; wU[w] = lq; }        // waves 4..7
    }
    __syncthreads();
    if (t == 0) {
      u64 A0 = wA[0];
      #pragma unroll
      for (int j = 1; j < 4; ++j) if (wA[j] > A0) A0 = wA[j];
      u64 PK = wS[4] + wS[5] + wS[6] + wS[7];
      int UN = wU[4] + wU[5] + wU[6] + wU[7];
      int psum = (int)(PK >> 32), inter = (int)(PK & 0xFFFFFFFFull);
      int idx = NN - 1 - (int)(A0 & 0x1FFFFFull);
      float sv = __uint_as_float((unsigned)(A0 >> 21));
      // accept: (float)inter/(float)max(psum,1) > 0.5f  <=>  2*inter > psum
      // (exact: 1<=psum<=2^21 -> ratio is >= 2^-22 away from 0.5 >> f32 ulp)
      int g = (sv >= 0.5f) ? 1 : 0;
      int a = (psum > 160 && 2 * inter > psum) ? 1 : 0;
      u64 pb = (tg << 52) | ((u64)(unsigned)g << 44) | ((u64)(unsigned)a << 43) |
               ((u64)(unsigned)UN << 21) | (u64)(unsigned)idx;
      #pragma unroll
      for (int r = 0; r < 8; ++r) slot_store(&c->pub[par][r][0], pb);
    }
  }

  // ---- consume: lane 0 of each wave polls its replica; in-register bcast ----
  u64 v = 0;
  if (lane == 0) {
    u64* p = &c->pub[par][w & 7][0];
    while (((v = slot_load(p)) >> 52) != tg) __builtin_amdgcn_s_sleep(1);
  }
  v = __shfl(v, 0);
  sidx = (int)(v & 0x1FFFFFull);
  un   = (int)((v >> 21) & 0x3FFFFFull);
  acc  = (int)((v >> 43) & 1ull);
  go   = (int)((v >> 44) & 1ull);
  // center + sigma: recomputed identically by every thread (read-only pred,
  // same op order as the reference -> grid-consistent decisions)
  cx = tanhf(pred[sidx])      + (2.0f / 2047.0f) * (float)(sidx & (WW - 1));
  cy = tanhf(pred[NN + sidx]) + (1.0f / 1023.0f) * (float)(sidx >> 11);
  s0 = expf(pred[2 * NN + sidx] * 10.0f);
  s1 = expf(pred[3 * NN + sidx] * 10.0f);
}

__global__ void init_kernel(Coord* c) {
  int t = blockIdx.x * blockDim.x + threadIdx.x;
  u64* p = (u64*)c;
  int n = (int)(sizeof(Coord) / 8);
  if (t < n) p[t] = 0;
}

__global__ __launch_bounds__(BLOCK, 1)
void cluster_kernel(const float* __restrict__ pred,
                    int* __restrict__ out,
                    Coord* __restrict__ c)
{
  #pragma clang fp contract(off)
  const int b = blockIdx.x, t = threadIdx.x;
  const int base = b * CHUNK;
  const int i0 = base + t * PXT;          // 16 contiguous pixels per thread

  const float xstep = 2.0f / 2047.0f;     // jnp.linspace(0,2,2048) step, f32
  const float ystep = 1.0f / 1023.0f;     // jnp.linspace(0,1,1024) step, f32

  // ---- stage 1: float4 loads, keep everything in registers ----
  float ex[PXT], ey[PXT], sd[PXT];
  unsigned mbits = 0, ubits;
  float bv = -1.0f; int bi = 0; int mc = 0;
  #pragma unroll
  for (int j = 0; j < 4; ++j) {
    float4 v0 = *reinterpret_cast<const float4*>(&pred[i0 + 4 * j]);
    float4 v1 = *reinterpret_cast<const float4*>(&pred[NN + i0 + 4 * j]);
    float4 v6 = *reinterpret_cast<const float4*>(&pred[6 * NN + i0 + 4 * j]);
    #pragma unroll
    for (int e = 0; e < 4; ++e) {
      const int k = 4 * j + e;
      const int i = i0 + k;
      float p0 = (e == 0) ? v0.x : (e == 1) ? v0.y : (e == 2) ? v0.z : v0.w;
      float p1 = (e == 0) ? v1.x : (e == 1) ? v1.y : (e == 2) ? v1.z : v1.w;
      float p6 = (e == 0) ? v6.x : (e == 1) ? v6.y : (e == 2) ? v6.z : v6.w;
      float seed = sigmoid_ref(p6);
      sd[k] = seed;
      unsigned m = (seed > 0.5f) ? 1u : 0u;
      mbits |= m << k;
      ex[k] = tanhf(p0) + xstep * (float)(i & (WW - 1));
      ey[k] = tanhf(p1) + ystep * (float)(i >> 11);
      mc += (int)m;
      float scv = m ? seed : 0.0f;
      if (scv > bv) { bv = scv; bi = i; }  // k ascending -> first max kept
    }
  }
  {
    int4 z = make_int4(0, 0, 0, 0);
    #pragma unroll
    for (int j = 0; j < 4; ++j)
      *reinterpret_cast<int4*>(&out[i0 + 4 * j]) = z;
  }
  ubits = mbits;

  int sidx, un, go, acc; float cx, cy, s0, s1;
  int tok = 1;
  barrier_exchange(c, pred, b, t, tok, bv, bi, mc, 0, 0,
                   sidx, un, go, acc, cx, cy, s0, s1); tok++;

  // ---- main loop: one slim two-hop barrier per iteration ----
  int count = 1;
  unsigned prev_pr = 0;
  for (int it = 0; it < 4000; ++it) {   // cap < 4096 so tag never aliases init 0
    // deferred label write for the previous segment (before break checks!)
    if (it && acc) {
      #pragma unroll
      for (int k = 0; k < PXT; ++k)
        if ((prev_pr >> k) & 1u) out[i0 + k] = count;
      count++;
    }
    if (un <= 160) break;          // cond: uncl.sum() > min_pixel
    if (!go) break;                // go == false -> stop, no state change

    // seed-pixel bit within this thread's contiguous 16 pixels
    int rel = sidx - base;
    unsigned sbit = 0;
    if ((rel >> 4) == t) sbit = 1u << (rel & 15);

    // proposal bits (decision-path math identical to reference)
    unsigned pr = 0;
    #pragma unroll
    for (int k = 0; k < PXT; ++k) {
      float dx = ex[k] - cx, dy = ey[k] - cy;
      float dsq = (dx * dx) * s0 + (dy * dy) * s1;
      float dist = expf(-dsq);
      pr |= ((dist > 0.5f) ? 1u : 0u) << k;
    }
    pr &= mbits;
    int lps = __popc(pr);
    int lin = __popc(pr & ubits & ~sbit);  // uncl2 & proposal
    ubits &= ~pr; ubits &= ~sbit;          // uncl_new
    int lu = __popc(ubits);

    // next-seed argmax over remaining unclustered (static indices only)
    bv = -1.0f; bi = 0;
    #pragma unroll
    for (int k = 0; k < PXT; ++k) {
      if (((ubits >> k) & 1u) && sd[k] > bv) { bv = sd[k]; bi = i0 + k; }
    }
    prev_pr = pr;
    barrier_exchange(c, pred, b, t, tok, bv, bi, lu, lps, lin,
                     sidx, un, go, acc, cx, cy, s0, s1); tok++;
  }
}

extern "C" void kernel_launch(void* const* d_in, const int* in_sizes, int n_in,
                              void* d_out, int out_size, void* d_ws, size_t ws_size,
                              hipStream_t stream) {
  const float* pred = (const float*)d_in[0];
  int* out = (int*)d_out;
  Coord* c = (Coord*)d_ws;

  init_kernel<<<dim3((unsigned)((sizeof(Coord)/8 + 255)/256)), dim3(256), 0, stream>>>(c);

  // Normal launch: 256 blocks x 512 threads = 1 block/CU on 256 CUs.
  cluster_kernel<<<dim3(GRID), dim3(BLOCK), 0, stream>>>(pred, out, c);
}

// Round 13
// 65.165 us; speedup vs baseline: 1.9302x; 1.0222x over previous
//
#include <hip/hip_runtime.h>

typedef unsigned long long u64;

#define HH 1024
#define WW 2048
#define NN (HH*WW)
#define GRID 256
#define BLOCK 512
#define PXT 16
#define CHUNK (PXT*BLOCK)       // 8192 pixels per block

// Split-aggregator two-hop barrier, fence-free tagged relaxed atomics.
//  A-slot : [tag:12][f32bits(val):30][NN-1-idx:21]  (u64 max == first-idx argmax)
//  B-slot : [tag:12][lps:14][lin:14][lu:14]         (block totals <= 8192)
//  pubA   : [tag:12][go:1][idx:21]   x16 replicas (block 0 aggregates A)
//  pubB   : [tag:12][acc:1][un:22]   x16 replicas (block 1 aggregates B)
struct Coord {
  u64 A[2][GRID];
  u64 B[2][GRID];
  u64 pubA[2][16][16];          // [par][replica][0] used; 128B-spaced lines
  u64 pubB[2][16][16];
};

// XLA expands logistic(x) as 0.5 + 0.5*tanh(0.5*x) — match that boundary.
__device__ __forceinline__ float sigmoid_ref(float x) {
  #pragma clang fp contract(off)
  return 0.5f + 0.5f * tanhf(0.5f * x);
}

__device__ __forceinline__ void slot_store(u64* p, u64 v) {
  __hip_atomic_store(p, v, __ATOMIC_RELAXED, __HIP_MEMORY_SCOPE_AGENT);
}
__device__ __forceinline__ u64 slot_load(u64* p) {
  return __hip_atomic_load(p, __ATOMIC_RELAXED, __HIP_MEMORY_SCOPE_AGENT);
}

// block-local packed reduce + arrival stores (all blocks)
__device__ __forceinline__ void block_arrive(Coord* c, int b, int t, int par, u64 tg,
                                             float bv, int bi, int lu, int lps, int lin,
                                             u64* wA, u64* wS) {
  const int w = t >> 6, lane = t & 63;
  unsigned fb = 0; int ic = 0;
  if (bv >= 0.0f) { fb = __float_as_uint(bv); ic = bi; }   // empty -> (0.0, idx 0)
  u64 am = ((u64)fb << 21) | (u64)(unsigned)(NN - 1 - ic);
  u64 sm = ((u64)(unsigned)lps << 42) | ((u64)(unsigned)lin << 21) | (u64)(unsigned)lu;
  for (int off = 32; off; off >>= 1) {
    u64 o = __shfl_xor(am, off); if (o > am) am = o;
    sm += __shfl_xor(sm, off);
  }
  if (lane == 0) { wA[w] = am; wS[w] = sm; }
  __syncthreads();
  if (t == 0) {
    u64 A0 = wA[0], S0 = wS[0];
    #pragma unroll
    for (int j = 1; j < 8; ++j) { if (wA[j] > A0) A0 = wA[j]; S0 += wS[j]; }
    slot_store(&c->A[par][b], (tg << 52) | A0);
    slot_store(&c->B[par][b], (tg << 52) | ((S0 >> 42) << 28) |
                              (((S0 >> 21) & 0x3FFFull) << 14) | (S0 & 0x3FFFull));
  }
  __syncthreads();   // t0's wA/wS reads complete before next reuse
}

__global__ void init_kernel(Coord* c) {
  int t = blockIdx.x * blockDim.x + threadIdx.x;
  u64* p = (u64*)c;
  int n = (int)(sizeof(Coord) / 8);
  if (t < n) p[t] = 0;
}

__global__ __launch_bounds__(BLOCK, 1)
void cluster_kernel(const float* __restrict__ pred,
                    int* __restrict__ out,
                    Coord* __restrict__ cc)
{
  #pragma clang fp contract(off)
  const int b = blockIdx.x, t = threadIdx.x;
  const int base = b * CHUNK;
  const int i0 = base + t * PXT;          // 16 contiguous pixels per thread
  const int w = t >> 6;

  __shared__ u64 wA[8], wS[8];            // arrive partials
  __shared__ u64 gP[4]; __shared__ u64 gS[4]; __shared__ int gU[4];
  __shared__ u64 shPA, shPB;

  const float xstep = 2.0f / 2047.0f;     // jnp.linspace(0,2,2048) step, f32
  const float ystep = 1.0f / 1023.0f;     // jnp.linspace(0,1,1024) step, f32

  // ---- stage 1: float4 loads, keep everything in registers ----
  float ex[PXT], ey[PXT], sd[PXT];
  unsigned mbits = 0, ubits;
  float bv = -1.0f; int bi = 0;
  #pragma unroll
  for (int j = 0; j < 4; ++j) {
    float4 v0 = *reinterpret_cast<const float4*>(&pred[i0 + 4 * j]);
    float4 v1 = *reinterpret_cast<const float4*>(&pred[NN + i0 + 4 * j]);
    float4 v6 = *reinterpret_cast<const float4*>(&pred[6 * NN + i0 + 4 * j]);
    #pragma unroll
    for (int e = 0; e < 4; ++e) {
      const int k = 4 * j + e;
      const int i = i0 + k;
      float p0 = (e == 0) ? v0.x : (e == 1) ? v0.y : (e == 2) ? v0.z : v0.w;
      float p1 = (e == 0) ? v1.x : (e == 1) ? v1.y : (e == 2) ? v1.z : v1.w;
      float p6 = (e == 0) ? v6.x : (e == 1) ? v6.y : (e == 2) ? v6.z : v6.w;
      float seed = sigmoid_ref(p6);
      sd[k] = seed;
      unsigned m = (seed > 0.5f) ? 1u : 0u;
      mbits |= m << k;
      ex[k] = tanhf(p0) + xstep * (float)(i & (WW - 1));
      ey[k] = tanhf(p1) + ystep * (float)(i >> 11);
      float scv = m ? seed : 0.0f;
      if (scv > bv) { bv = scv; bi = i; }  // k ascending -> first max kept
    }
  }
  {
    int4 z = make_int4(0, 0, 0, 0);
    #pragma unroll
    for (int j = 0; j < 4; ++j)
      *reinterpret_cast<int4*>(&out[i0 + 4 * j]) = z;
  }
  ubits = mbits;

  int tok = 1;
  block_arrive(cc, b, t, tok & 1, (u64)(unsigned)(tok & 0xFFF),
               bv, bi, __popc(mbits), 0, 0, wA, wS);

  // ---- main loop ----
  int count = 1;
  unsigned prev_pr = 0;
  for (int it = 0; it < 4000; ++it) {   // cap < 4096 so tag never aliases init 0
    const int par = tok & 1;
    const u64 tg = (u64)(unsigned)(tok & 0xFFF);

    // ======== B aggregator (block 1): gather + publish FIRST ========
    if (b == 1) {
      u64 pk = 0; int lq = 0;
      if (t < GRID) {
        u64 v; u64* p = &cc->B[par][t];
        while (((v = slot_load(p)) >> 52) != tg) __builtin_amdgcn_s_sleep(1);
        int lp = (int)((v >> 28) & 0x3FFFull);
        int ln = (int)((v >> 14) & 0x3FFFull);
        lq = (int)(v & 0x3FFFull);
        pk = ((u64)(unsigned)lp << 32) | (unsigned)ln;
      }
      for (int off = 32; off; off >>= 1) { pk += __shfl_xor(pk, off); lq += __shfl_xor(lq, off); }
      if ((t & 63) == 0 && w < 4) { gS[w] = pk; gU[w] = lq; }
      __syncthreads();
      if (t == 0) {
        u64 PK = gS[0] + gS[1] + gS[2] + gS[3];
        int UN = gU[0] + gU[1] + gU[2] + gU[3];
        int psum = (int)(PK >> 32), inter = (int)(PK & 0xFFFFFFFFull);
        // accept: (float)inter/(float)max(psum,1) > 0.5f  <=>  2*inter > psum
        // (exact: 1<=psum<=2^21 -> ratio >= 2^-22 away from 0.5 >> f32 ulp)
        int a = (psum > 160 && 2 * inter > psum) ? 1 : 0;
        u64 pbv = (tg << 52) | ((u64)(unsigned)a << 22) | (u64)(unsigned)UN;
        #pragma unroll
        for (int r = 0; r < 16; ++r) slot_store(&cc->pubB[par][r][0], pbv);
        shPB = pbv;
      }
      __syncthreads();
    }

    // ======== A side: aggregate (block 0) or poll pubA ========
    u64 pa;
    if (b == 0) {
      u64 m = 0;
      if (t < GRID) {
        u64 v; u64* p = &cc->A[par][t];
        while (((v = slot_load(p)) >> 52) != tg) __builtin_amdgcn_s_sleep(1);
        m = v & ((1ull << 52) - 1);
      }
      for (int off = 32; off; off >>= 1) { u64 o = __shfl_xor(m, off); if (o > m) m = o; }
      if ((t & 63) == 0 && w < 4) gP[w] = m;
      __syncthreads();
      if (t == 0) {
        u64 M = gP[0];
        #pragma unroll
        for (int j = 1; j < 4; ++j) if (gP[j] > M) M = gP[j];
        int idx = NN - 1 - (int)(M & 0x1FFFFFull);
        float sv = __uint_as_float((unsigned)(M >> 21));
        int g = (sv >= 0.5f) ? 1 : 0;
        u64 pav = (tg << 52) | ((u64)(unsigned)g << 21) | (u64)(unsigned)idx;
        #pragma unroll
        for (int r = 0; r < 16; ++r) slot_store(&cc->pubA[par][r][0], pav);
        shPA = pav;
      }
      __syncthreads();
      pa = shPA;
    } else {
      u64 v = 0;
      if ((t & 63) == 0) {
        u64* p = &cc->pubA[par][(b * 8 + w) & 15][0];
        while (((v = slot_load(p)) >> 52) != tg) __builtin_amdgcn_s_sleep(1);
      }
      pa = __shfl(v, 0);
    }
    int sidx = (int)(pa & 0x1FFFFFull);
    int go   = (int)((pa >> 21) & 1ull);

    // center + sigma (identical math/op-order to reference; grid-consistent)
    float cx = tanhf(pred[sidx])      + xstep * (float)(sidx & (WW - 1));
    float cy = tanhf(pred[NN + sidx]) + ystep * (float)(sidx >> 11);
    float s0 = expf(pred[2 * NN + sidx] * 10.0f);
    float s1 = expf(pred[3 * NN + sidx] * 10.0f);

    // speculative proposal bits (committed only after break checks)
    unsigned pr = 0;
    #pragma unroll
    for (int k = 0; k < PXT; ++k) {
      float dx = ex[k] - cx, dy = ey[k] - cy;
      float dsq = (dx * dx) * s0 + (dy * dy) * s1;
      float dist = expf(-dsq);
      pr |= ((dist > 0.5f) ? 1u : 0u) << k;
    }
    pr &= mbits;

    // ======== B side consume (latency hidden under pr-loop) ========
    u64 pb;
    if (b == 1) pb = shPB;
    else {
      u64 v = 0;
      if ((t & 63) == 0) {
        u64* p = &cc->pubB[par][(b * 8 + w) & 15][0];
        while (((v = slot_load(p)) >> 52) != tg) __builtin_amdgcn_s_sleep(1);
      }
      pb = __shfl(v, 0);
    }
    int un  = (int)(pb & 0x3FFFFFull);
    int acc = (int)((pb >> 22) & 1ull);

    // deferred label write for the previous segment (before break checks!)
    if (it && acc) {
      #pragma unroll
      for (int k = 0; k < PXT; ++k)
        if ((prev_pr >> k) & 1u) out[i0 + k] = count;
      count++;
    }
    if (un <= 160) break;          // cond: uncl.sum() > min_pixel
    if (!go) break;                // go == false -> stop, no state change

    // commit state
    int rel = sidx - base;
    unsigned sbit = 0;
    if ((rel >> 4) == t) sbit = 1u << (rel & 15);
    int lps = __popc(pr);
    int lin = __popc(pr & ubits & ~sbit);  // uncl2 & proposal
    ubits &= ~pr; ubits &= ~sbit;          // uncl_new
    int lu = __popc(ubits);

    // next-seed argmax over remaining unclustered (static indices only)
    bv = -1.0f; bi = 0;
    #pragma unroll
    for (int k = 0; k < PXT; ++k) {
      if (((ubits >> k) & 1u) && sd[k] > bv) { bv = sd[k]; bi = i0 + k; }
    }
    prev_pr = pr;
    tok++;
    block_arrive(cc, b, t, tok & 1, (u64)(unsigned)(tok & 0xFFF),
                 bv, bi, lu, lps, lin, wA, wS);
  }
}

extern "C" void kernel_launch(void* const* d_in, const int* in_sizes, int n_in,
                              void* d_out, int out_size, void* d_ws, size_t ws_size,
                              hipStream_t stream) {
  const float* pred = (const float*)d_in[0];
  int* out = (int*)d_out;
  Coord* c = (Coord*)d_ws;

  init_kernel<<<dim3((unsigned)((sizeof(Coord)/8 + 255)/256)), dim3(256), 0, stream>>>(c);

  // Normal launch: 256 blocks x 512 threads = 1 block/CU on 256 CUs.
  cluster_kernel<<<dim3(GRID), dim3(BLOCK), 0, stream>>>(pred, out, c);
}